// Round 1
// 325.466 us; speedup vs baseline: 1.0494x; 1.0494x over previous
//
#include <hip/hip_runtime.h>
#include <math.h>

#define LM 64      // L_MODES
#define MM 127     // 2L-1
#define GG 128     // GRID
#define CC 64      // CIN
#define OO 64      // COUT

#define TWO_PI 6.28318530717958647692f

// ---------------------------------------------------------------------------
// K1: fused DFT + conv-channel-sum + (block 512) time-MLP precompute.
// Blocks 0..511: b = (t, cq). 16 channels per block. 256 threads:
//   k = tx&63, cg = tx>>6 (4 ch each).
//   F[(t*64+k)*CC + c] = sum_n x[t,n,c] e^{-i 2pi k n/128} * (2pi/G)*quad_w[t]
//   Sv[cq][t][n] = (cq==0)*bsum + sum_{c in quarter} x[t,n,c]*cwsum[c]
// Block 512: aux = [psi(128) | tvec(64)]
__global__ __launch_bounds__(256) void k_dft(const float* __restrict__ x,
                                             const float* __restrict__ quad_w,
                                             const float* __restrict__ conv_w,
                                             const float* __restrict__ conv_b,
                                             const float* __restrict__ t_emb,
                                             const float* __restrict__ dense_w,
                                             const float* __restrict__ time_w,
                                             float2* __restrict__ F,
                                             float* __restrict__ Sv,
                                             float* __restrict__ aux) {
    int b = blockIdx.x;
    int tx = threadIdx.x;

    if (b == 512) {
        // time-MLP: psi = t_emb @ dense_w ; tvec[o] = sum_j time_w[o,j]*psi[j]
        __shared__ float psis[128];
        if (tx < 128) {
            float acc = 0.f;
            for (int tq = 0; tq < 256; ++tq) acc += t_emb[tq] * dense_w[tq * 128 + tx];
            psis[tx] = acc;
            aux[tx] = acc;
        }
        __syncthreads();
        if (tx < 64) {
            float tv = 0.f;
            for (int q = 0; q < 64; ++q) tv += time_w[tx * 64 + q] * psis[q];
            aux[128 + tx] = tv;
        }
        return;
    }

    int t = b >> 2, cq = b & 3;
    int c0base = cq * 16;

    __shared__ __align__(16) float xs[GG * 16];  // [n][c-local] 8 KB
    __shared__ float2 tab[GG];
    __shared__ float cwsl[16];
    __shared__ float Sp[2][GG];
    __shared__ float bsum_s;

    // stage x[t][:, c0base..c0base+16) -- float4 coalesced
    {
        const float* xp = x + (size_t)t * GG * CC + c0base;
        for (int idx = tx; idx < GG * 16 / 4; idx += 256) {
            int n = idx >> 2, c4 = idx & 3;
            *(float4*)&xs[n * 16 + c4 * 4] = *(const float4*)&xp[n * CC + c4 * 4];
        }
    }
    if (tx < GG) {
        float ang = (TWO_PI / GG) * tx;
        tab[tx] = make_float2(cosf(ang), sinf(ang));
    }
    if (tx >= 128 && tx < 144) {
        int c = c0base + (tx - 128);
        float s = 0.f;
        for (int o = 0; o < OO; ++o) s += conv_w[c * OO + o];
        cwsl[tx - 128] = s;
    }
    if (tx == 144) {
        float bs = 0.f;
        for (int o = 0; o < OO; ++o) bs += conv_b[o];
        bsum_s = bs;
    }
    __syncthreads();

    int k = tx & 63, cg = tx >> 6;
    int c0 = cg * 4;

    float sr[4], si[4];
#pragma unroll
    for (int j = 0; j < 4; ++j) { sr[j] = 0.f; si[j] = 0.f; }

    int kn = 0;
#pragma unroll 4
    for (int n = 0; n < GG; ++n) {
        float2 w = tab[kn];
        const float4 v = *(const float4*)&xs[n * 16 + c0];
        float vv[4] = {v.x, v.y, v.z, v.w};
#pragma unroll
        for (int j = 0; j < 4; ++j) {
            sr[j] += vv[j] * w.x;
            si[j] -= vv[j] * w.y;
        }
        kn = (kn + k) & (GG - 1);
    }
    float sc = (TWO_PI / GG) * quad_w[t];

    // direct store: 4 channels = 2 float4 per thread
    {
        float2* Fp = F + ((size_t)t * 64 + k) * CC + c0base + c0;
        *(float4*)&Fp[0] = make_float4(sr[0] * sc, si[0] * sc, sr[1] * sc, si[1] * sc);
        *(float4*)&Fp[2] = make_float4(sr[2] * sc, si[2] * sc, sr[3] * sc, si[3] * sc);
    }

    // conv channel-sum partial over this block's 16 channels (xs still valid)
    {
        int n2 = tx & 127, h = tx >> 7;  // h in {0,1}, 8 channels each
        float p = 0.f;
#pragma unroll
        for (int j = 0; j < 8; ++j) p += xs[n2 * 16 + h * 8 + j] * cwsl[h * 8 + j];
        Sp[h][n2] = p;
    }
    __syncthreads();
    if (tx < GG) {
        float v = Sp[0][tx] + Sp[1][tx] + (cq == 0 ? bsum_s : 0.f);
        Sv[(size_t)cq * GG * GG + t * GG + tx] = v;
    }
}

// ---------------------------------------------------------------------------
// K2: forward Legendre, t-split 4 ways into partial sums.
// Block per (m, l-half, t-quarter). 256 threads: c = tx&63, lg = tx>>6 (8 l each).
// flmp[tq][l][m][c] = sum_{t in quarter} F[t,m,c] * P_in[l,m,t]
__global__ __launch_bounds__(256) void k_leg_fwd(const float2* __restrict__ F,
                                                 const float* __restrict__ P_in,
                                                 float2* __restrict__ flmp) {
    int m = blockIdx.x;      // 0..63
    int lh = blockIdx.y;     // 0..1
    int tq = blockIdx.z;     // 0..3
    int l0 = lh * 32;
    if (l0 + 31 < m) return;
    int t0 = tq * 32;

    __shared__ __align__(16) float2 Fs[32 * 64];   // 16 KB
    __shared__ __align__(16) float  Ps[32 * 36];   // 4.5 KB
    int tx = threadIdx.x;
    int c = tx & 63, lg = tx >> 6;

    for (int idx = tx; idx < 32 * 32; idx += 256) {
        int lr = idx >> 5, tl = idx & 31;
        Ps[tl * 36 + lr] = P_in[((size_t)(l0 + lr) * MM + 63 + m) * GG + t0 + tl];
    }
    for (int idx = tx; idx < 32 * 64; idx += 256) {
        int tl = idx >> 6, cc = idx & 63;
        Fs[idx] = F[((size_t)(t0 + tl) * 64 + m) * CC + cc];
    }
    __syncthreads();

    float sr[8], si[8];
#pragma unroll
    for (int j = 0; j < 8; ++j) { sr[j] = 0.f; si[j] = 0.f; }

#pragma unroll 2
    for (int tl = 0; tl < 32; ++tl) {
        float2 f = Fs[tl * 64 + c];
        const float* pp = &Ps[tl * 36 + lg * 8];
        float4 p0 = *(const float4*)pp;
        float4 p1 = *(const float4*)(pp + 4);
        float pv[8] = {p0.x, p0.y, p0.z, p0.w, p1.x, p1.y, p1.z, p1.w};
#pragma unroll
        for (int j = 0; j < 8; ++j) {
            sr[j] += f.x * pv[j];
            si[j] += f.y * pv[j];
        }
    }
#pragma unroll
    for (int j = 0; j < 8; ++j) {
        int l = l0 + lg * 8 + j;
        if (l >= m)
            flmp[(((size_t)tq * 64 + l) * 64 + m) * CC + c] = make_float2(sr[j], si[j]);
    }
}

// ---------------------------------------------------------------------------
// K3: complex channel mix, float4 weight loads. Block per (l,mi), 256 threads.
// Thread: ol = tx&15 (o = 4*ol..4*ol+3), ig = tx>>4 (i = 4*ig..4*ig+3).
__global__ __launch_bounds__(256) void k_wmul(const float2* __restrict__ flmp,
                                              const float* __restrict__ wr,
                                              const float* __restrict__ wi,
                                              float2* __restrict__ flm2) {
    int l = blockIdx.x, mi = blockIdx.y;
    int m = mi - 63;
    int am = m < 0 ? -m : m;
    if (l < am) return;
    __shared__ float2 fs[CC];
    __shared__ float2 part[16][CC];  // 8 KB
    int tx = threadIdx.x, ol = tx & 15, ig = tx >> 4;
    if (tx < 64) {
        float2 f = make_float2(0.f, 0.f);
#pragma unroll
        for (int q = 0; q < 4; ++q) {
            float2 v = flmp[(((size_t)q * 64 + l) * 64 + am) * CC + tx];
            f.x += v.x;
            f.y += v.y;
        }
        if (m < 0) {
            float sgn = (am & 1) ? -1.f : 1.f;
            f.x *= sgn;
            f.y *= -sgn;
        }
        fs[tx] = f;
    }
    __syncthreads();
    size_t base = ((size_t)(l * MM + mi) * CC) * OO;
    const float4* wr4 = (const float4*)(wr + base);
    const float4* wi4 = (const float4*)(wi + base);
    float ar[4] = {0.f, 0.f, 0.f, 0.f}, ai[4] = {0.f, 0.f, 0.f, 0.f};
#pragma unroll
    for (int di = 0; di < 4; ++di) {
        int i = ig * 4 + di;
        float4 a = wr4[i * 16 + ol];
        float4 b = wi4[i * 16 + ol];
        float2 f = fs[i];
        ar[0] += f.x * a.x - f.y * b.x;  ai[0] += f.x * b.x + f.y * a.x;
        ar[1] += f.x * a.y - f.y * b.y;  ai[1] += f.x * b.y + f.y * a.y;
        ar[2] += f.x * a.z - f.y * b.z;  ai[2] += f.x * b.z + f.y * a.z;
        ar[3] += f.x * a.w - f.y * b.w;  ai[3] += f.x * b.w + f.y * a.w;
    }
#pragma unroll
    for (int j = 0; j < 4; ++j) part[ig][ol * 4 + j] = make_float2(ar[j], ai[j]);
    __syncthreads();
    if (tx < 64) {
        float rr = 0.f, ri = 0.f;
#pragma unroll
        for (int q = 0; q < 16; ++q) {
            float2 p = part[q][tx];
            rr += p.x;
            ri += p.y;
        }
        flm2[(size_t)(l * MM + mi) * OO + tx] = make_float2(rr, ri);
    }
}

// ---------------------------------------------------------------------------
// K4: inverse Legendre. Block per (mi, th(4) x oh(2)), 256 threads.
__global__ __launch_bounds__(256) void k_leg_inv(const float2* __restrict__ flm2,
                                                 const float* __restrict__ P_out,
                                                 float2* __restrict__ g) {
    int mi = blockIdx.x;
    int th = blockIdx.y >> 1, oh = blockIdx.y & 1;
    int t0 = th * 32, o0 = oh * 32;

    __shared__ __align__(16) float2 Ws[64 * 32]; // 16 KB
    __shared__ __align__(16) float  Ps[64 * 32]; // 8 KB
    int tx = threadIdx.x;
    int ol = tx & 31, tg = tx >> 5;   // tg in 0..7, 4 t each
    int o = o0 + ol;

    for (int idx = tx; idx < 64 * 32; idx += 256) {
        int ls = idx >> 5, oo = idx & 31;
        Ws[idx] = flm2[(size_t)(ls * MM + mi) * OO + o0 + oo];
    }
    for (int idx = tx; idx < 64 * 32; idx += 256) {
        int ls = idx >> 5, tt = idx & 31;
        Ps[idx] = P_out[((size_t)ls * MM + mi) * GG + t0 + tt];
    }
    __syncthreads();

    float gr[4], gi[4];
#pragma unroll
    for (int j = 0; j < 4; ++j) { gr[j] = 0.f; gi[j] = 0.f; }

#pragma unroll 2
    for (int l = 0; l < 64; ++l) {
        float2 wv = Ws[l * 32 + ol];
        const float4 p = *(const float4*)&Ps[l * 32 + tg * 4];
        float pv[4] = {p.x, p.y, p.z, p.w};
#pragma unroll
        for (int j = 0; j < 4; ++j) {
            gr[j] += wv.x * pv[j];
            gi[j] += wv.y * pv[j];
        }
    }
#pragma unroll
    for (int j = 0; j < 4; ++j) {
        int t = t0 + tg * 4 + j;
        g[((size_t)t * MM + mi) * OO + o] = make_float2(gr[j], gi[j]);
    }
}

// ---------------------------------------------------------------------------
// K5: Fourier synthesis (Horner) + time-mod branch + LN + ReLU.
// e^{-i63phi} via identity: 63phi = pi*k - phi  =>  c63 = (-1)^k c, s63 = -(-1)^k s.
__global__ __launch_bounds__(512) void k_final(const float2* __restrict__ g,
                                               const float* __restrict__ Sv,
                                               const float* __restrict__ aux,
                                               const float* __restrict__ ln_scale,
                                               const float* __restrict__ ln_bias,
                                               float* __restrict__ out) {
    __shared__ float2 gs[64 * 64]; // 32 KB, two mi-passes
    __shared__ float Ss[64];
    int t = blockIdx.x, kh = blockIdx.y;
    int tx = threadIdx.x;
    int o = tx & 63, kg = tx >> 6;

    if (tx < 64) {
        float s = 0.f;
#pragma unroll
        for (int q = 0; q < 4; ++q) s += Sv[(size_t)q * GG * GG + t * GG + kh * 64 + tx];
        Ss[tx] = s;
    }

    float zr[8], zi[8], accr[8], acci[8];
#pragma unroll
    for (int j = 0; j < 8; ++j) {
        int k = kh * 64 + kg * 8 + j;
        float phi = (TWO_PI / GG) * k;
        float s, c;
        sincosf(phi, &s, &c);   // precise, one-time
        zr[j] = c; zi[j] = s;
        accr[j] = 0.f; acci[j] = 0.f;
    }

    for (int pass = 0; pass < 2; ++pass) {
        int mbase = (pass == 0) ? 64 : 0;
        int cnt = (pass == 0) ? 63 : 64;
        __syncthreads();
        for (int idx = tx; idx < cnt * 64; idx += 512) {
            int mm = idx >> 6, oo = idx & 63;
            gs[idx] = g[((size_t)t * MM + mbase + mm) * OO + oo];
        }
        __syncthreads();
        for (int mm = cnt - 1; mm >= 0; --mm) {
            float2 gv = gs[mm * 64 + o];
#pragma unroll
            for (int j = 0; j < 8; ++j) {
                float tr = accr[j] * zr[j] - acci[j] * zi[j] + gv.x;
                float ti = accr[j] * zi[j] + acci[j] * zr[j] + gv.y;
                accr[j] = tr; acci[j] = ti;
            }
        }
    }

    float tvec = aux[128 + o], bt = aux[64 + o];
    float lns = ln_scale[o], lnb = ln_bias[o];
#pragma unroll
    for (int j = 0; j < 8; ++j) {
        int k = kh * 64 + kg * 8 + j;
        float sgn = (k & 1) ? -1.f : 1.f;
        // Re(e^{-i63phi} * H) with c63 = sgn*zr, s63 = -sgn*zi:
        float xsp = sgn * (accr[j] * zr[j] - acci[j] * zi[j]);
        float val = xsp + tvec * Ss[k - kh * 64] + bt;

        float mu = val;
#pragma unroll
        for (int off = 1; off < 64; off <<= 1) mu += __shfl_xor(mu, off);
        mu *= (1.f / 64.f);
        float d = val - mu;
        float var = d * d;
#pragma unroll
        for (int off = 1; off < 64; off <<= 1) var += __shfl_xor(var, off);
        var *= (1.f / 64.f);
        float r = d * rsqrtf(var + 1e-6f) * lns + lnb;
        out[((size_t)(t * GG) + k) * OO + o] = fmaxf(r, 0.f);
    }
}

// ---------------------------------------------------------------------------
extern "C" void kernel_launch(void* const* d_in, const int* in_sizes, int n_in,
                              void* d_out, int out_size, void* d_ws, size_t ws_size,
                              hipStream_t stream) {
    const float* x        = (const float*)d_in[0];
    const float* t_emb    = (const float*)d_in[1];
    const float* wr       = (const float*)d_in[2];
    const float* wi       = (const float*)d_in[3];
    const float* conv_w   = (const float*)d_in[4];
    const float* conv_b   = (const float*)d_in[5];
    const float* time_w   = (const float*)d_in[6];
    const float* dense_w  = (const float*)d_in[7];
    const float* ln_scale = (const float*)d_in[8];
    const float* ln_bias  = (const float*)d_in[9];
    const float* P_in     = (const float*)d_in[10];
    const float* P_out    = (const float*)d_in[11];
    const float* quad_w   = (const float*)d_in[12];

    float* ws = (float*)d_ws;
    float*  aux  = ws;                         // 512 floats
    float2* F    = (float2*)(ws + 512);        // 524288 f2  -> ends 1049088
    float2* flmp = (float2*)(ws + 1049088);    // 4x262144 f2 -> ends 3146240
    float2* flm2 = (float2*)(ws + 3146240);    // 520192 f2  -> ends 4186624
    float2* g    = (float2*)(ws + 4186624);    // 1040384 f2 -> ends 6267392
    float*  Sv   = ws + 6267392;               // 65536 (4 x 128 x 128)

    float* out = (float*)d_out;

    k_dft<<<513, 256, 0, stream>>>(x, quad_w, conv_w, conv_b, t_emb, dense_w, time_w,
                                   F, Sv, aux);
    k_leg_fwd<<<dim3(64, 2, 4), 256, 0, stream>>>(F, P_in, flmp);
    k_wmul<<<dim3(LM, MM), 256, 0, stream>>>(flmp, wr, wi, flm2);
    k_leg_inv<<<dim3(MM, 8), 256, 0, stream>>>(flm2, P_out, g);
    k_final<<<dim3(GG, 2), 512, 0, stream>>>(g, Sv, aux, ln_scale, ln_bias, out);
}